// Round 6
// baseline (196.537 us; speedup 1.0000x reference)
//
#include <hip/hip_runtime.h>
#include <math.h>

typedef __attribute__((ext_vector_type(8))) short short8;
typedef __attribute__((ext_vector_type(4))) float f32x4;

#define BB 8
#define CC 256
#define OO 256
#define HH 56
#define WW 56
#define HWH 3136
#define RED 16

__device__ inline unsigned short f2bf(float f) {
    unsigned u = __builtin_bit_cast(unsigned, f);
    u = (u + 0x7fffu + ((u >> 16) & 1u)) >> 16;
    return (unsigned short)u;
}
__device__ inline float bf2f(unsigned short h) {
    return __builtin_bit_cast(float, ((unsigned)h) << 16);
}
__device__ inline unsigned cvtpk(float lo, float hi) {
    unsigned r;
    asm("v_cvt_pk_bf16_f32 %0, %1, %2" : "=v"(r) : "v"(lo), "v"(hi));
    return r;
}
__device__ inline float fast_tanh(float x) {
    float e = __expf(2.0f * x);
    return 1.0f - 2.0f / (e + 1.0f);
}
__device__ inline void gl2lds16(const void* g, void* l) {
    __builtin_amdgcn_global_load_lds((const __attribute__((address_space(1))) unsigned int*)g,
                                     (__attribute__((address_space(3))) unsigned int*)l, 16, 0, 0);
}

// ---------------- zero y ----------------
__global__ __launch_bounds__(256) void zero_y(float* __restrict__ y) {
    y[blockIdx.x * 256 + threadIdx.x] = 0.f;
}

// ---------------- NCHW f32 -> NHWC bf16 (pure transpose) ----------------
__global__ __launch_bounds__(256) void prep_xt(const float* __restrict__ x, unsigned short* __restrict__ x_t) {
    __shared__ float t[64][65];
    int blk = blockIdx.x;
    int ct = blk & 3;
    int hwt = (blk >> 2) % 49;
    int b = blk / (4 * 49);
    int c0 = ct * 64, hw0 = hwt * 64;
    int tid = threadIdx.x;
    const float* xb = x + ((size_t)(b * CC + c0)) * HWH + hw0;
    #pragma unroll
    for (int it = 0; it < 16; ++it) {
        int idx = it * 256 + tid;
        int c = idx >> 6, px = idx & 63;
        t[c][px] = xb[(size_t)c * HWH + px];
    }
    __syncthreads();
    unsigned short* xo = x_t + ((size_t)(b * HWH + hw0)) * CC + c0;
    #pragma unroll
    for (int it = 0; it < 16; ++it) {
        int idx = it * 256 + tid;
        int px = idx >> 6, c = idx & 63;
        xo[(size_t)px * CC + c] = f2bf(t[c][px]);
    }
}

// ---------------- SE: channel sums from bf16 NHWC ----------------
__global__ __launch_bounds__(256) void se_sum(const unsigned short* __restrict__ x_t, float* __restrict__ y) {
    __shared__ float sm[8][256];
    int blk = blockIdx.x;              // 392 = 8b * 49
    int b = blk / 49;
    int px0 = (blk % 49) * 64;
    int tid = threadIdx.x;
    int wk = tid >> 5;                 // 8 row-walkers
    int cg = tid & 31;                 // 32 x 16B column groups
    float sum[8] = {0.f, 0.f, 0.f, 0.f, 0.f, 0.f, 0.f, 0.f};
    const unsigned short* base = x_t + ((size_t)(b * HWH + px0)) * 256 + cg * 8;
    #pragma unroll
    for (int i = 0; i < 8; ++i) {
        short8 v = *(const short8*)(base + (size_t)(wk + i * 8) * 256);
        #pragma unroll
        for (int e = 0; e < 8; ++e) sum[e] += bf2f((unsigned short)v[e]);
    }
    #pragma unroll
    for (int e = 0; e < 8; ++e) sm[wk][cg * 8 + e] = sum[e];
    __syncthreads();
    float t = 0.f;
    #pragma unroll
    for (int w = 0; w < 8; ++w) t += sm[w][tid];
    atomicAdd(&y[b * 256 + tid], t);
}

// ---------------- SE: fc1->relu->fc2->sigmoid (y holds sums) ----------------
__global__ __launch_bounds__(256) void se_fc(const float* __restrict__ y, const float* __restrict__ fc1,
                                             const float* __restrict__ fc2, float* __restrict__ s) {
    __shared__ float hbuf[BB * RED];
    const float inv = 1.0f / HWH;
    int t = threadIdx.x;
    if (t < BB * RED) {
        int b = t / RED, r = t % RED;
        float acc = 0.f;
        for (int c = 0; c < CC; ++c) acc += (y[b * CC + c] * inv) * fc1[r * CC + c];
        hbuf[t] = fmaxf(acc, 0.f);
    }
    __syncthreads();
    for (int i = t; i < BB * CC; i += 256) {
        int b = i / CC, c = i % CC;
        float acc = 0.f;
        #pragma unroll
        for (int r = 0; r < RED; ++r) acc += hbuf[b * RED + r] * fc2[c * RED + r];
        s[i] = 1.0f / (1.0f + expf(-acc));
    }
}

// ---------------- deform weights -> per-b, per-MFMA-fragment layout, scaled by s ----------------
// within b: idx2 = ((t*8 + og)*4 + f)*64 + lane ; f = n*2+kh
// value = w_conv[o][c][kk] * s[b][c]; o = og*32+n*16+(lane&15), c = (t&3)*64+kh*32+(lane>>4)*8+e, kk = t>>2
__global__ __launch_bounds__(256) void prep_wcf8(const float* __restrict__ w_conv, const float* __restrict__ s,
                                                 unsigned short* __restrict__ wbf) {
    int idx = blockIdx.x * 256 + threadIdx.x;   // 8*36*8*4*64 = 589824
    int lane = idx & 63;
    int f = (idx >> 6) & 3;
    int og = (idx >> 8) & 7;
    int bt = idx >> 11;
    int b = bt / 36, t = bt - b * 36;
    int kk = t >> 2, cc = t & 3;
    int n = f >> 1, kh = f & 1;
    int o = og * 32 + n * 16 + (lane & 15);
    int cb2 = cc * 64 + kh * 32 + ((lane >> 4) << 3);
    short8 r;
    #pragma unroll
    for (int e = 0; e < 8; ++e)
        r[e] = (short)f2bf(w_conv[(size_t)(o * 256 + cb2 + e) * 9 + kk] * s[b * 256 + cb2 + e]);
    *(short8*)(wbf + (size_t)idx * 8) = r;
}

// ---------------- offset weights -> 36 pre-swizzled 4KB tiles (o padded to 32, unscaled) ----------------
__global__ __launch_bounds__(256) void prep_wo(const float* __restrict__ w_off, unsigned short* __restrict__ wbo) {
    int idx = blockIdx.x * 256 + threadIdx.x;    // 36*32*8 = 9216
    int g = idx & 7;
    int o = (idx >> 3) & 31;
    int t = idx >> 8;
    int kk = t >> 2, cc = t & 3;
    int dst = (((o * 128 + g * 16) ^ ((o & 7) << 4)) >> 1);
    short8 r;
    #pragma unroll
    for (int e = 0; e < 8; ++e) {
        int c = cc * 64 + g * 8 + e;
        r[e] = (o < 18) ? (short)f2bf(w_off[(size_t)(o * 256 + c) * 9 + kk]) : (short)0;
    }
    *(short8*)(wbo + (size_t)t * 2048 + dst) = r;
}

// ---------------- offset conv via MFMA: 784 blocks, 32px x 32o, A scaled by s from LDS ----------------
__global__ __launch_bounds__(256) void offset_mfma(const unsigned short* __restrict__ x_t,
                                                   const float* __restrict__ s,
                                                   const unsigned short* __restrict__ wbo,
                                                   const float* __restrict__ b_off,
                                                   float* __restrict__ offs) {
    __shared__ __align__(16) char As[4][4096];
    __shared__ __align__(16) char Bs[4][4096];
    __shared__ float red[128 * 8];
    __shared__ float s_lds[256];
    int blk = blockIdx.x;
    blk = (blk & 7) * 98 + (blk >> 3);
    int b = blk / 98;
    int hw0 = (blk % 98) * 32;
    int tid = threadIdx.x;
    int lane = tid & 63, wv = tid >> 6;
    int ks = wv >> 1, m = wv & 1;
    int r0 = lane & 15, kb = (lane >> 4) << 4;
    int px = tid >> 3, c8 = tid & 7;
    int hwp = hw0 + px;
    int hp = hwp / 56, wp_ = hwp - hp * 56;
    int awoff = (px * 128 + c8 * 16) ^ ((px & 7) << 4);
    f32x4 zero = {0.f, 0.f, 0.f, 0.f};
    f32x4 acc[2] = {zero, zero};

    s_lds[tid] = s[b * 256 + tid];
    __syncthreads();

    auto buildA = [&](int q, int r, int buf) {
        int t = q * 18 + r;
        int kk = t >> 2, cc = t & 3;
        int hh = hp + kk / 3 - 1, ww = wp_ + kk % 3 - 1;
        short8 v = {0, 0, 0, 0, 0, 0, 0, 0};
        if (hh >= 0 && hh < 56 && ww >= 0 && ww < 56)
            v = *(const short8*)(x_t + (((size_t)(b * HWH + hh * 56 + ww)) << 8) + cc * 64 + c8 * 8);
        float4 s0 = *(const float4*)&s_lds[cc * 64 + c8 * 8];
        float4 s1 = *(const float4*)&s_lds[cc * 64 + c8 * 8 + 4];
        float f0 = bf2f((unsigned short)v[0]) * s0.x;
        float f1 = bf2f((unsigned short)v[1]) * s0.y;
        float f2 = bf2f((unsigned short)v[2]) * s0.z;
        float f3 = bf2f((unsigned short)v[3]) * s0.w;
        float f4 = bf2f((unsigned short)v[4]) * s1.x;
        float f5 = bf2f((unsigned short)v[5]) * s1.y;
        float f6 = bf2f((unsigned short)v[6]) * s1.z;
        float f7 = bf2f((unsigned short)v[7]) * s1.w;
        *(uint4*)(As[q * 2 + buf] + awoff) =
            make_uint4(cvtpk(f0, f1), cvtpk(f2, f3), cvtpk(f4, f5), cvtpk(f6, f7));
    };
    auto stageB = [&](int q, int r, int buf) {
        int t = q * 18 + r;
        gl2lds16(wbo + (size_t)t * 2048 + tid * 8, Bs[q * 2 + buf] + (tid >> 6) * 1024);
    };

    stageB(0, 0, 0); stageB(1, 0, 0);
    buildA(0, 0, 0); buildA(1, 0, 0);
    __syncthreads();

    #pragma unroll 2
    for (int r = 0; r < 18; ++r) {
        int cur = r & 1;
        if (r < 17) {
            stageB(0, r + 1, cur ^ 1); stageB(1, r + 1, cur ^ 1);
            buildA(0, r + 1, cur ^ 1); buildA(1, r + 1, cur ^ 1);
        }
        short8 a[2];
        #pragma unroll
        for (int kh = 0; kh < 2; ++kh) {
            int row = m * 16 + r0;
            int ao = (row * 128 + kh * 64 + kb) ^ ((row & 7) << 4);
            a[kh] = *(const short8*)(As[ks * 2 + cur] + ao);
        }
        #pragma unroll
        for (int n = 0; n < 2; ++n)
            #pragma unroll
            for (int kh = 0; kh < 2; ++kh) {
                int brow = n * 16 + r0;
                int bo = (brow * 128 + kh * 64 + kb) ^ ((brow & 7) << 4);
                short8 bv = *(const short8*)(Bs[ks * 2 + cur] + bo);
                acc[n] = __builtin_amdgcn_mfma_f32_16x16x32_bf16(a[kh], bv, acc[n], 0, 0, 0);
            }
        __syncthreads();
    }

    if (ks == 1) {
        #pragma unroll
        for (int n = 0; n < 2; ++n)
            *(f32x4*)&red[(m * 64 + lane) * 8 + n * 4] = acc[n];
    }
    __syncthreads();
    if (ks == 0) {
        #pragma unroll
        for (int n = 0; n < 2; ++n) {
            f32x4 o2 = *(const f32x4*)&red[(m * 64 + lane) * 8 + n * 4];
            acc[n] += o2;
            int o = n * 16 + r0;
            if (o < 18) {
                float bia = b_off[o];
                #pragma unroll
                for (int j = 0; j < 4; ++j)
                    offs[((size_t)(b * 18 + o)) * HWH + hw0 + m * 16 + ((lane >> 4) << 2) + j] = acc[n][j] + bia;
            }
        }
    }
}

// ---------------- precompute bilinear coords: bases (int4) + packed bf16 weights (uint2) ----------------
__global__ __launch_bounds__(256) void coords_prep(const float* __restrict__ offs,
                                                   int4* __restrict__ ci, uint2* __restrict__ cfp) {
    int idx = blockIdx.x * 256 + threadIdx.x;    // 8*9*3136 = 225792
    int hw = idx % 3136;
    int t = idx / 3136;
    int kk = t % 9;
    int b = t / 9;
    int h = hw / 56, w = hw - h * 56;
    float dy = offs[((size_t)(b * 18 + kk * 2)) * HWH + hw];
    float dx = offs[((size_t)(b * 18 + kk * 2 + 1)) * HWH + hw];
    float ys = (float)(h - 1 + kk / 3) + dy;
    float xs = (float)(w - 1 + kk % 3) + dx;
    float y0f = floorf(ys), x0f = floorf(xs);
    float wy = ys - y0f, wx = xs - x0f;
    int y0 = (int)y0f, x0 = (int)x0f;
    int bi[4]; float wt[4];
    #pragma unroll
    for (int j = 0; j < 4; ++j) {
        int yj = y0 + (j >> 1), xj = x0 + (j & 1);
        bool val = yj >= 0 && yj < 56 && xj >= 0 && xj < 56;
        int yc = min(max(yj, 0), 55), xc = min(max(xj, 0), 55);
        wt[j] = val ? ((j >> 1) ? wy : 1.f - wy) * ((j & 1) ? wx : 1.f - wx) : 0.f;
        bi[j] = (b * HWH + yc * 56 + xc) << 8;
    }
    ci[idx] = make_int4(bi[0], bi[1], bi[2], bi[3]);
    cfp[idx] = make_uint2(cvtpk(wt[0], wt[1]), cvtpk(wt[2], wt[3]));
}

// ---------------- deformable conv: 784 blocks x 512 thr, 32px x 256o, pipelined prefetch ----------------
__global__ __launch_bounds__(512, 4) void deform_mfma(const unsigned short* __restrict__ x_t,
                                                      const int4* __restrict__ ci,
                                                      const uint2* __restrict__ cfp,
                                                      const unsigned short* __restrict__ wbf,
                                                      const float* __restrict__ b_conv,
                                                      float* __restrict__ out) {
    __shared__ __align__(16) char As[16384];     // 4 tiles x 4KB
    int blk = blockIdx.x;
    blk = (blk & 7) * 98 + (blk >> 3);           // 784 = 8*98, bijective; b == XCD id
    int b = blk / 98;
    int hw0 = (blk % 98) * 32;
    int tid = threadIdx.x;
    int lane = tid & 63, og = tid >> 6;
    int px = tid >> 4, c8 = tid & 15;
    int r0 = lane & 15, kb = (lane >> 4) << 4;
    int cidxB = b * 9 * HWH + hw0 + px;
    int awoff = (px * 128 + (c8 & 7) * 16) ^ ((px & 7) << 4);
    int atile = (c8 >> 3) * 4096;
    const unsigned short* wbB = wbf + (size_t)b * 589824 + og * 2048 + lane * 8;

    f32x4 zero = {0.f, 0.f, 0.f, 0.f};
    f32x4 acc[2][2];
    #pragma unroll
    for (int m = 0; m < 2; ++m)
        #pragma unroll
        for (int n = 0; n < 2; ++n) acc[m][n] = zero;

    int4 cbN;
    unsigned cwC0, cwC1, cwN0, cwN1;
    short8 crn0[4], crn1[4];
    short8 bv[8];

    // ---- prologue ----
    {
        int4 cb0 = ci[cidxB];
        uint2 w0 = cfp[cidxB];
        cbN = ci[cidxB + HWH];
        uint2 w1 = cfp[cidxB + HWH];
        cwC0 = w0.x; cwC1 = w0.y; cwN0 = w1.x; cwN1 = w1.y;
        int ch0 = c8 * 8;
        crn0[0] = *(const short8*)(x_t + cb0.x + ch0);
        crn0[1] = *(const short8*)(x_t + cb0.y + ch0);
        crn0[2] = *(const short8*)(x_t + cb0.z + ch0);
        crn0[3] = *(const short8*)(x_t + cb0.w + ch0);
        // B(0)
        #pragma unroll
        for (int f = 0; f < 4; ++f) {
            bv[f] = *(const short8*)(wbB + f * 512);
            bv[4 + f] = *(const short8*)(wbB + 16384 + f * 512);
        }
        // corners pair1 (half 1, same kk0)
        crn1[0] = *(const short8*)(x_t + cb0.x + 128 + ch0);
        crn1[1] = *(const short8*)(x_t + cb0.y + 128 + ch0);
        crn1[2] = *(const short8*)(x_t + cb0.z + 128 + ch0);
        crn1[3] = *(const short8*)(x_t + cb0.w + 128 + ch0);
        // bilinear pair0 -> tiles 0/1
        float fw0 = __builtin_bit_cast(float, cwC0 << 16);
        float fw1 = __builtin_bit_cast(float, cwC0 & 0xffff0000u);
        float fw2 = __builtin_bit_cast(float, cwC1 << 16);
        float fw3 = __builtin_bit_cast(float, cwC1 & 0xffff0000u);
        float f[8];
        #pragma unroll
        for (int e = 0; e < 8; ++e) {
            float fv = fw0 * bf2f((unsigned short)crn0[0][e]);
            fv = fmaf(fw1, bf2f((unsigned short)crn0[1][e]), fv);
            fv = fmaf(fw2, bf2f((unsigned short)crn0[2][e]), fv);
            fv = fmaf(fw3, bf2f((unsigned short)crn0[3][e]), fv);
            f[e] = fv;
        }
        *(uint4*)(As + atile + awoff) =
            make_uint4(cvtpk(f[0], f[1]), cvtpk(f[2], f[3]), cvtpk(f[4], f[5]), cvtpk(f[6], f[7]));
    }
    __syncthreads();

#define DSTEP(P, CRNU, CRNF, CW0, CW1, ODD) { \
    short8 aq0[2][2], aq1[2][2]; \
    int tb = ((P) & 1) * 8192; \
    _Pragma("unroll") for (int m_ = 0; m_ < 2; ++m_) \
      _Pragma("unroll") for (int kh_ = 0; kh_ < 2; ++kh_) { \
        int row_ = m_ * 16 + r0; \
        int ao_ = (row_ * 128 + kh_ * 64 + kb) ^ ((row_ & 7) << 4); \
        aq0[m_][kh_] = *(const short8*)(As + tb + ao_); \
        aq1[m_][kh_] = *(const short8*)(As + tb + 4096 + ao_); } \
    __builtin_amdgcn_s_setprio(1); \
    _Pragma("unroll") for (int n_ = 0; n_ < 2; ++n_) \
      _Pragma("unroll") for (int kh_ = 0; kh_ < 2; ++kh_) \
        _Pragma("unroll") for (int m_ = 0; m_ < 2; ++m_) { \
          acc[m_][n_] = __builtin_amdgcn_mfma_f32_16x16x32_bf16(aq0[m_][kh_], bv[n_ * 2 + kh_], acc[m_][n_], 0, 0, 0); \
          acc[m_][n_] = __builtin_amdgcn_mfma_f32_16x16x32_bf16(aq1[m_][kh_], bv[4 + n_ * 2 + kh_], acc[m_][n_], 0, 0, 0); } \
    __builtin_amdgcn_s_setprio(0); \
    if ((P) < 17) { \
        const unsigned short* wp_ = wbB + (size_t)((P) + 1) * 32768; \
        _Pragma("unroll") for (int q_ = 0; q_ < 4; ++q_) { \
            bv[q_] = *(const short8*)(wp_ + q_ * 512); \
            bv[4 + q_] = *(const short8*)(wp_ + 16384 + q_ * 512); } } \
    if ((P) < 16) { \
        int chF = ((P) & 1) * 128 + c8 * 8; \
        CRNF[0] = *(const short8*)(x_t + cbN.x + chF); \
        CRNF[1] = *(const short8*)(x_t + cbN.y + chF); \
        CRNF[2] = *(const short8*)(x_t + cbN.z + chF); \
        CRNF[3] = *(const short8*)(x_t + cbN.w + chF); } \
    if ((P) < 17) { \
        float fw0 = __builtin_bit_cast(float, (CW0) << 16); \
        float fw1 = __builtin_bit_cast(float, (CW0) & 0xffff0000u); \
        float fw2 = __builtin_bit_cast(float, (CW1) << 16); \
        float fw3 = __builtin_bit_cast(float, (CW1) & 0xffff0000u); \
        float f_[8]; \
        _Pragma("unroll") for (int e_ = 0; e_ < 8; ++e_) { \
            float fv_ = fw0 * bf2f((unsigned short)CRNU[0][e_]); \
            fv_ = fmaf(fw1, bf2f((unsigned short)CRNU[1][e_]), fv_); \
            fv_ = fmaf(fw2, bf2f((unsigned short)CRNU[2][e_]), fv_); \
            fv_ = fmaf(fw3, bf2f((unsigned short)CRNU[3][e_]), fv_); \
            f_[e_] = fv_; } \
        int tw_ = ((((P) + 1) & 1) << 1) * 4096 + atile + awoff; \
        *(uint4*)(As + tw_) = \
            make_uint4(cvtpk(f_[0], f_[1]), cvtpk(f_[2], f_[3]), cvtpk(f_[4], f_[5]), cvtpk(f_[6], f_[7])); } \
    if (ODD) { \
        cwC0 = cwN0; cwC1 = cwN1; \
        int kkL_ = ((P) + 3) >> 1; \
        if (kkL_ <= 8) { \
            cbN = ci[cidxB + kkL_ * HWH]; \
            uint2 wn_ = cfp[cidxB + kkL_ * HWH]; \
            cwN0 = wn_.x; cwN1 = wn_.y; } } \
    __syncthreads(); }

    #pragma unroll 1
    for (int k = 0; k < 9; ++k) {
        int PE = 2 * k, PO = 2 * k + 1;
        DSTEP(PE, crn1, crn0, cwC0, cwC1, 0);
        DSTEP(PO, crn0, crn1, cwN0, cwN1, 1);
    }

    // ---- epilogue: bias + tanh, NCHW float4 stores ----
    #pragma unroll
    for (int n = 0; n < 2; ++n) {
        int o = og * 32 + n * 16 + r0;
        float bia = b_conv[o];
        #pragma unroll
        for (int m = 0; m < 2; ++m) {
            int pxo = hw0 + m * 16 + ((lane >> 4) << 2);
            float4 v;
            v.x = fast_tanh(acc[m][n][0] + bia);
            v.y = fast_tanh(acc[m][n][1] + bia);
            v.z = fast_tanh(acc[m][n][2] + bia);
            v.w = fast_tanh(acc[m][n][3] + bia);
            *(float4*)(out + ((size_t)(b * OO + o)) * HWH + pxo) = v;
        }
    }
#undef DSTEP
}

extern "C" void kernel_launch(void* const* d_in, const int* in_sizes, int n_in,
                              void* d_out, int out_size, void* d_ws, size_t ws_size,
                              hipStream_t stream) {
    const float* x      = (const float*)d_in[0];
    const float* w_off  = (const float*)d_in[1];
    const float* b_off  = (const float*)d_in[2];
    const float* w_conv = (const float*)d_in[3];
    const float* b_conv = (const float*)d_in[4];
    const float* fc1    = (const float*)d_in[5];
    const float* fc2    = (const float*)d_in[6];
    float* out = (float*)d_out;
    float* ws  = (float*)d_ws;

    float* y    = ws;                                  // 2048 f32
    float* s    = y + 2048;                            // 2048
    float* offs = s + 2048;                            // 451584
    unsigned short* x_t = (unsigned short*)(offs + 451584);    // 6,422,528 shorts
    unsigned short* wbo = x_t + 6422528;                       // 73,728 shorts
    unsigned short* wbf = wbo + 73728;                         // 4,718,592 shorts (8 per-b copies)
    int4*  ci  = (int4*)(wbf + 4718592);                       // 225,792 int4
    uint2* cfp = (uint2*)(ci + 225792);                        // 225,792 uint2

    prep_xt<<<BB * 49 * 4, 256, 0, stream>>>(x, x_t);
    zero_y<<<8, 256, 0, stream>>>(y);
    se_sum<<<BB * 49, 256, 0, stream>>>(x_t, y);
    se_fc<<<1, 256, 0, stream>>>(y, fc1, fc2, s);
    prep_wo<<<36, 256, 0, stream>>>(w_off, wbo);
    prep_wcf8<<<2304, 256, 0, stream>>>(w_conv, s, wbf);
    offset_mfma<<<BB * 98, 256, 0, stream>>>(x_t, s, wbo, b_off, offs);
    coords_prep<<<882, 256, 0, stream>>>(offs, ci, cfp);
    deform_mfma<<<BB * 98, 512, 0, stream>>>(x_t, ci, cfp, wbf, b_conv, out);
}